// Round 23
// baseline (153.912 us; speedup 1.0000x reference)
//
#include <hip/hip_runtime.h>

// Problem constants
#define Bn  4
#define Cn  128
#define CQn 64
#define Nn  4096

typedef _Float16 h8_t __attribute__((ext_vector_type(8)));
typedef __fp16   p2_t __attribute__((ext_vector_type(2)));   // cvt_pkrtz result type
typedef float    f32x4 __attribute__((ext_vector_type(4)));
typedef unsigned int u32;

// ws layout (bytes):
//  Qh: [B][N][64]  f16 at 0         (2 MB)   Q pre-scaled by log2(e)
//  Kh: [B][N][64]  f16 at 2 MB      (2 MB)
//  Vg: [B][64 jt][128 c][64 pos] f16 at 4 MB (4 MB)  -- fragment-major V
//  pPart: [B][64 it][S][128 c][64 q] f16 at 8 MB   (S x 4 MB)  NORMALIZED o/l
//  pMl:   [B][64 it][S][64 q][2]    f32 after      (S x 128 KB)

#define QKV_BYTES   8388608ull
#define PART_PER_S  4194304ull
#define ML_PER_S    131072ull
#define LOG2E       1.44269504f

// ---------------------------------------------------------------------------
// Kernel 1: QKV projection via MFMA -- R20 VERBATIM (proven).
// ---------------------------------------------------------------------------
__global__ __launch_bounds__(256) void qkv_proj(
    const float* __restrict__ x,
    const float* __restrict__ Wq, const float* __restrict__ bq,
    const float* __restrict__ Wk, const float* __restrict__ bk,
    const float* __restrict__ Wv, const float* __restrict__ bv,
    _Float16* __restrict__ Qh, _Float16* __restrict__ Kh, _Float16* __restrict__ Vg)
{
    __shared__ _Float16 XsT[64][136];   // [n][ch], 272B row stride

    const int nt   = blockIdx.x;
    const int ot   = blockIdx.y;
    const int b    = blockIdx.z;
    const int tid  = threadIdx.x;
    const int w    = tid >> 6;
    const int lane = tid & 63;
    const int g    = lane >> 4;
    const int ln   = lane & 15;
    const int nbase = nt * 64;

    const float* xb = x + (size_t)b * Cn * Nn + nbase;
    #pragma unroll
    for (int u = 0; u < 8; ++u) {
        int f  = tid + u * 256;
        int c  = f >> 4;
        int n4 = (f & 15) * 4;
        float4 v = *(const float4*)&xb[(size_t)c * Nn + n4];
        XsT[n4 + 0][c] = (_Float16)v.x;
        XsT[n4 + 1][c] = (_Float16)v.y;
        XsT[n4 + 2][c] = (_Float16)v.z;
        XsT[n4 + 3][c] = (_Float16)v.w;
    }
    __syncthreads();

    const float* Wsrc; const float* bsrc;
    if      (ot == 0) { Wsrc = Wq;            bsrc = bq;      }
    else if (ot == 1) { Wsrc = Wk;            bsrc = bk;      }
    else if (ot == 2) { Wsrc = Wv;            bsrc = bv;      }
    else              { Wsrc = Wv + 64 * Cn;  bsrc = bv + 64; }

    union H8 { h8_t h; _Float16 e[8]; };

    const int os = w;
    f32x4 acc[4];
    #pragma unroll
    for (int ns = 0; ns < 4; ++ns) acc[ns] = (f32x4){0.f, 0.f, 0.f, 0.f};

    #pragma unroll
    for (int kc = 0; kc < 4; ++kc) {
        const float* wp = Wsrc + (size_t)(os * 16 + ln) * Cn + kc * 32 + 8 * g;
        float4 wa = *(const float4*)wp;
        float4 wb = *(const float4*)(wp + 4);
        H8 t;
        t.e[0] = (_Float16)wa.x; t.e[1] = (_Float16)wa.y;
        t.e[2] = (_Float16)wa.z; t.e[3] = (_Float16)wa.w;
        t.e[4] = (_Float16)wb.x; t.e[5] = (_Float16)wb.y;
        t.e[6] = (_Float16)wb.z; t.e[7] = (_Float16)wb.w;
        const h8_t wf = t.h;
        #pragma unroll
        for (int ns = 0; ns < 4; ++ns) {
            const h8_t xv = *(const h8_t*)&XsT[ns * 16 + ln][kc * 32 + 8 * g];
            acc[ns] = __builtin_amdgcn_mfma_f32_16x16x32_f16(wf, xv, acc[ns], 0, 0, 0);
        }
    }

    if (ot <= 1) {
        union H4 { _Float16 e[4]; short4 s; };
        _Float16* dst = (ot == 0 ? Qh : Kh) + ((size_t)b * Nn + nbase) * CQn;
        const float sc = (ot == 0) ? LOG2E : 1.f;
        float4 bb = *(const float4*)&bsrc[os * 16 + 4 * g];
        #pragma unroll
        for (int ns = 0; ns < 4; ++ns) {
            H4 h;
            h.e[0] = (_Float16)((acc[ns][0] + bb.x) * sc);
            h.e[1] = (_Float16)((acc[ns][1] + bb.y) * sc);
            h.e[2] = (_Float16)((acc[ns][2] + bb.z) * sc);
            h.e[3] = (_Float16)((acc[ns][3] + bb.w) * sc);
            *(short4*)&dst[(size_t)(ns * 16 + ln) * CQn + os * 16 + 4 * g] = h.s;
        }
    } else {
        _Float16* dst = Vg + (size_t)(b * 64 + nt) * 8192;
        const int cbase = (ot - 2) * 64 + os * 16 + 4 * g;
        #pragma unroll
        for (int ns = 0; ns < 4; ++ns) {
            const int pos = 32 * (ns >> 1) + 8 * ((4 * ns + (ln >> 2)) & 3)
                          + 4 * (ns & 1) + (ln & 3);
            #pragma unroll
            for (int r = 0; r < 4; ++r) {
                dst[(size_t)(cbase + r) * 64 + pos] =
                    (_Float16)(acc[ns][r] + bsrc[os * 16 + 4 * g + r]);
            }
        }
    }
}

// ---------------------------------------------------------------------------
// Kernel 2: MFMA flash attention -- V DIRECT FROM GLOBAL (R13's proven
// formulas), enabled by the allocator model: static LDS padded to 36 KB
// (only 16 KB used: K double-buffer) -> max 4 blocks/CU -> 128-VGPR budget
// (R13 died at 16 KB LDS -> 64-cap -> spill). Removes 2/3 of LDS traffic
// (V reads were 16 KB/wave/tile) and stageV + one barrier per tile.
// Schedule: stageK(t+1) at top -> scores(t) -> preload V cs0..3 ->
// softmax (covers V-half-1) -> pack P -> load V cs4..7 -> PV half1
// (covers V-half-2) -> PV half2 -> barrier (drains stageK, full-tile cover).
// V fragment addresses (R13-verified): lane(g,ln), cs: 16B at
//   Vg[tile][c=cs*16+ln][8g] and [32+8g].
// ---------------------------------------------------------------------------
__device__ __forceinline__ void gload16(const void* g, void* l) {
    __builtin_amdgcn_global_load_lds(
        (const __attribute__((address_space(1))) u32*)g,
        (__attribute__((address_space(3))) u32*)l, 16, 0, 0);
}

#define KOFF0 0          // K buffer 0: 8 KB
#define KOFF1 8192       // K buffer 1: 8 KB
// bytes 16384..36863: dead pad -> caps occupancy at 4 blocks/CU -> 128-reg budget

__global__ __launch_bounds__(256) void attn_split(
    const _Float16* __restrict__ Qh, const _Float16* __restrict__ Kh,
    const _Float16* __restrict__ Vg, float* __restrict__ out,
    _Float16* __restrict__ pPart, float* __restrict__ pMl, int S)
{
    __shared__ __align__(16) char smem[36864];

    const int tid  = threadIdx.x;
    const int w    = tid >> 6;
    const int lane = tid & 63;
    const int g    = lane >> 4;
    const int ln   = lane & 15;
    const int it   = blockIdx.x;
    const int b    = blockIdx.y;
    const int s    = blockIdx.z;
    const int wib  = it * 64 + w * 16;
    const int njt  = 64 / S;

    const _Float16* qrow = Qh + ((size_t)(b * Nn + wib + ln)) * CQn + 8 * g;
    const h8_t q0 = *(const h8_t*)(qrow);
    const h8_t q1 = *(const h8_t*)(qrow + 32);

    const _Float16* Kb  = Kh + (size_t)b * Nn * CQn;
    const _Float16* Vgb = Vg + (size_t)b * 64 * 8192;

    int ks[2];
    #pragma unroll
    for (int u = 0; u < 2; ++u) {
        int G   = u * 256 + tid;
        int row = G >> 3;
        ks[u] = row * CQn + (((G & 7) ^ (row & 7)) * 8);
    }

    const int r7  = ln & 7;
    const int kb0 = ln * 128 + (((    g) ^ r7) << 4);
    const int kb1 = ln * 128 + (((4 + g) ^ r7) << 4);

    auto stageK = [&](int koff, int jt) {
        const _Float16* src = Kb + (size_t)jt * 64 * CQn;
        #pragma unroll
        for (int u = 0; u < 2; ++u)
            gload16(src + ks[u], smem + koff + u * 4096 + w * 1024);
    };

    f32x4 oacc[8];
    #pragma unroll
    for (int i = 0; i < 8; ++i) oacc[i] = (f32x4){0.f, 0.f, 0.f, 0.f};
    float m_run = -3.0e38f, l_run = 0.f;

    const int jt0 = s * njt;
    stageK(KOFF0, jt0);
    __syncthreads();

    for (int t = 0; t < njt; ++t) {
        // 1) stage next K tile into the other buffer (drains at end barrier
        //    with full-tile cover)
        if (t + 1 < njt) stageK((t & 1) ? KOFF0 : KOFF1, jt0 + t + 1);

        // per-lane V base for this tile (fragment-major)
        const _Float16* vt = Vgb + (size_t)(jt0 + t) * 8192 + (size_t)ln * 64 + 8 * g;

        // 2) scores from K LDS: st[js] rows = keys js*16+4g+r, col = query ln
        const char* KU = smem + ((t & 1) ? KOFF1 : KOFF0);
        f32x4 st[4];
        __builtin_amdgcn_s_setprio(1);
        #pragma unroll
        for (int js = 0; js < 4; ++js) {
            h8_t k0 = *(const h8_t*)(KU + kb0 + js * 2048);
            h8_t k1 = *(const h8_t*)(KU + kb1 + js * 2048);
            st[js] = (f32x4){0.f, 0.f, 0.f, 0.f};
            st[js] = __builtin_amdgcn_mfma_f32_16x16x32_f16(k0, q0, st[js], 0, 0, 0);
            st[js] = __builtin_amdgcn_mfma_f32_16x16x32_f16(k1, q1, st[js], 0, 0, 0);
        }
        __builtin_amdgcn_s_setprio(0);

        // 3) preload V half 1 (cs 0..3) -- latency hides under softmax
        h8_t va0[4], va1[4];
        #pragma unroll
        for (int cs = 0; cs < 4; ++cs) {
            va0[cs] = *(const h8_t*)(vt + cs * 1024);
            va1[cs] = *(const h8_t*)(vt + cs * 1024 + 32);
        }

        // 4) online softmax in exp2 domain, defer-max THR = 8*log2e = 11.54
        float tmax = st[0][0];
        #pragma unroll
        for (int js = 0; js < 4; ++js)
            #pragma unroll
            for (int r = 0; r < 4; ++r) tmax = fmaxf(tmax, st[js][r]);
        tmax = fmaxf(tmax, __shfl_xor(tmax, 16));
        tmax = fmaxf(tmax, __shfl_xor(tmax, 32));
        if (__any(tmax > m_run + 11.54f)) {
            const float mnew  = fmaxf(m_run, tmax);
            const float alpha = __builtin_amdgcn_exp2f(m_run - mnew);
            const float a0 = __shfl(alpha, 4 * g + 0);
            const float a1 = __shfl(alpha, 4 * g + 1);
            const float a2 = __shfl(alpha, 4 * g + 2);
            const float a3 = __shfl(alpha, 4 * g + 3);
            #pragma unroll
            for (int cs = 0; cs < 8; ++cs) {
                oacc[cs][0] *= a0; oacc[cs][1] *= a1;
                oacc[cs][2] *= a2; oacc[cs][3] *= a3;
            }
            l_run *= alpha;
            m_run = mnew;
        }
        float ts = 0.f;
        #pragma unroll
        for (int js = 0; js < 4; ++js)
            #pragma unroll
            for (int r = 0; r < 4; ++r) {
                float p = __builtin_amdgcn_exp2f(st[js][r] - m_run);
                st[js][r] = p;
                ts += p;
            }
        ts += __shfl_xor(ts, 16);
        ts += __shfl_xor(ts, 32);
        l_run += ts;

        // 5) P fragments via packed cvt (kappa(e,g) = 4g+(e&3)+16*(e>>2))
        union H8P { h8_t h; p2_t p2[4]; };
        H8P p0u, p1u;
        p0u.p2[0] = __builtin_amdgcn_cvt_pkrtz(st[0][0], st[0][1]);
        p0u.p2[1] = __builtin_amdgcn_cvt_pkrtz(st[0][2], st[0][3]);
        p0u.p2[2] = __builtin_amdgcn_cvt_pkrtz(st[1][0], st[1][1]);
        p0u.p2[3] = __builtin_amdgcn_cvt_pkrtz(st[1][2], st[1][3]);
        p1u.p2[0] = __builtin_amdgcn_cvt_pkrtz(st[2][0], st[2][1]);
        p1u.p2[1] = __builtin_amdgcn_cvt_pkrtz(st[2][2], st[2][3]);
        p1u.p2[2] = __builtin_amdgcn_cvt_pkrtz(st[3][0], st[3][1]);
        p1u.p2[3] = __builtin_amdgcn_cvt_pkrtz(st[3][2], st[3][3]);
        const h8_t pa0 = p0u.h;
        const h8_t pa1 = p1u.h;

        // 6) load V half 2 (cs 4..7) -- latency hides under PV half 1 + TLP
        h8_t vb0[4], vb1[4];
        #pragma unroll
        for (int cs = 0; cs < 4; ++cs) {
            vb0[cs] = *(const h8_t*)(vt + (cs + 4) * 1024);
            vb1[cs] = *(const h8_t*)(vt + (cs + 4) * 1024 + 32);
        }

        // 7) PV
        __builtin_amdgcn_s_setprio(1);
        #pragma unroll
        for (int cs = 0; cs < 4; ++cs) {
            oacc[cs] = __builtin_amdgcn_mfma_f32_16x16x32_f16(pa0, va0[cs], oacc[cs], 0, 0, 0);
            oacc[cs] = __builtin_amdgcn_mfma_f32_16x16x32_f16(pa1, va1[cs], oacc[cs], 0, 0, 0);
        }
        #pragma unroll
        for (int cs = 0; cs < 4; ++cs) {
            oacc[cs + 4] = __builtin_amdgcn_mfma_f32_16x16x32_f16(pa0, vb0[cs], oacc[cs + 4], 0, 0, 0);
            oacc[cs + 4] = __builtin_amdgcn_mfma_f32_16x16x32_f16(pa1, vb1[cs], oacc[cs + 4], 0, 0, 0);
        }
        __builtin_amdgcn_s_setprio(0);

        __syncthreads();   // single barrier: drains stageK(t+1), retires K reads
    }

    const float lr = 1.f / l_run;
    const float l0 = __shfl(lr, 4 * g + 0);
    const float l1 = __shfl(lr, 4 * g + 1);
    const float l2 = __shfl(lr, 4 * g + 2);
    const float l3 = __shfl(lr, 4 * g + 3);

    if (S == 1) {
        float* ob = out + (size_t)b * Cn * Nn;
        #pragma unroll
        for (int cs = 0; cs < 8; ++cs) {
            float4 o;
            o.x = oacc[cs][0] * l0;
            o.y = oacc[cs][1] * l1;
            o.z = oacc[cs][2] * l2;
            o.w = oacc[cs][3] * l3;
            *(float4*)&ob[(size_t)(cs * 16 + ln) * Nn + wib + 4 * g] = o;
        }
    } else {
        union H4 { _Float16 e[4]; short4 sv; };
        _Float16* pp = pPart + (((size_t)b * 64 + it) * S + s) * 8192;
        const int qloc = w * 16 + 4 * g;
        #pragma unroll
        for (int cs = 0; cs < 8; ++cs) {
            H4 h;
            h.e[0] = (_Float16)(oacc[cs][0] * l0);
            h.e[1] = (_Float16)(oacc[cs][1] * l1);
            h.e[2] = (_Float16)(oacc[cs][2] * l2);
            h.e[3] = (_Float16)(oacc[cs][3] * l3);
            *(short4*)&pp[(size_t)(cs * 16 + ln) * 64 + qloc] = h.sv;
        }
        if (g == 0) {
            float* ml = pMl + ((((size_t)b * 64 + it) * S + s) * 64 + w * 16 + ln) * 2;
            ml[0] = m_run;
            ml[1] = l_run;
        }
    }
}

// ---------------------------------------------------------------------------
// Kernel 3: flash-combine across S splits -- R20 VERBATIM.
// grid (64 it, B, 2 c-halves) = 512 blocks.
// ---------------------------------------------------------------------------
__global__ __launch_bounds__(256) void attn_combine(
    const _Float16* __restrict__ pPart, const float* __restrict__ pMl,
    float* __restrict__ out, int S)
{
    const int it  = blockIdx.x;
    const int b   = blockIdx.y;
    const int ch  = blockIdx.z;
    const int tid = threadIdx.x;

    __shared__ float wgt[4][64];
    __shared__ float linv[64];

    if (tid < 64) {
        const float* mlb = pMl + (((size_t)b * 64 + it) * S * 64 + tid) * 2;
        float ms[4], ls[4], m = -3.0e38f;
        for (int s = 0; s < S; ++s) {
            ms[s] = mlb[s * 128 + 0];
            ls[s] = mlb[s * 128 + 1];
            m = fmaxf(m, ms[s]);
        }
        float l = 0.f;
        for (int s = 0; s < S; ++s) {
            float wv = ls[s] * __builtin_amdgcn_exp2f(ms[s] - m);
            wgt[s][tid] = wv;
            l += wv;
        }
        linv[tid] = 1.f / l;
    }
    __syncthreads();

    const int c  = ch * 64 + (tid >> 2);
    const int q0 = (tid & 3) * 16;
    const _Float16* base = pPart + ((size_t)b * 64 + it) * S * 8192 + (size_t)c * 64 + q0;

    float acc[16];
    #pragma unroll
    for (int k = 0; k < 16; ++k) acc[k] = 0.f;
    for (int s = 0; s < S; ++s) {
        const _Float16* ps = base + (size_t)s * 8192;
        #pragma unroll
        for (int k = 0; k < 16; k += 8) {
            h8_t v = *(const h8_t*)(ps + k);
            #pragma unroll
            for (int j = 0; j < 8; ++j)
                acc[k + j] += wgt[s][q0 + k + j] * (float)v[j];
        }
    }
    float* ob = out + ((size_t)b * Cn + c) * Nn + it * 64 + q0;
    #pragma unroll
    for (int k = 0; k < 16; k += 4) {
        float4 o;
        o.x = acc[k + 0] * linv[q0 + k + 0];
        o.y = acc[k + 1] * linv[q0 + k + 1];
        o.z = acc[k + 2] * linv[q0 + k + 2];
        o.w = acc[k + 3] * linv[q0 + k + 3];
        *(float4*)&ob[k] = o;
    }
}

extern "C" void kernel_launch(void* const* d_in, const int* in_sizes, int n_in,
                              void* d_out, int out_size, void* d_ws, size_t ws_size,
                              hipStream_t stream) {
    const float* x  = (const float*)d_in[0];
    const float* Wq = (const float*)d_in[1];
    const float* bq = (const float*)d_in[2];
    const float* Wk = (const float*)d_in[3];
    const float* bk = (const float*)d_in[4];
    const float* Wv = (const float*)d_in[5];
    const float* bv = (const float*)d_in[6];
    float* out = (float*)d_out;

    _Float16* ws = (_Float16*)d_ws;
    _Float16* Qh = ws;
    _Float16* Kh = ws + 1048576;
    _Float16* Vg = ws + 2097152;

    int S = 1;
    if (ws_size >= QKV_BYTES + 4 * (PART_PER_S + ML_PER_S)) S = 4;
    else if (ws_size >= QKV_BYTES + 2 * (PART_PER_S + ML_PER_S)) S = 2;

    _Float16* pPart = (_Float16*)((char*)d_ws + QKV_BYTES);
    float*    pMl   = (float*)((char*)d_ws + QKV_BYTES + (size_t)S * PART_PER_S);

    dim3 gproj(Nn / 64, 4, Bn);
    qkv_proj<<<gproj, 256, 0, stream>>>(x, Wq, bq, Wk, bk, Wv, bv, Qh, Kh, Vg);

    dim3 gattn(Nn / 64, Bn, S);
    attn_split<<<gattn, 256, 0, stream>>>(Qh, Kh, Vg, out, pPart, pMl, S);

    if (S > 1) {
        dim3 gcomb(Nn / 64, Bn, 2);
        attn_combine<<<gcomb, 256, 0, stream>>>(pPart, pMl, out, S);
    }
}

// Round 24
// 65.868 us; speedup vs baseline: 2.3367x; 2.3367x over previous
//
#include <hip/hip_runtime.h>

// Problem constants
#define Bn  4
#define Cn  128
#define CQn 64
#define Nn  4096

typedef _Float16 h8_t __attribute__((ext_vector_type(8)));
typedef __fp16   p2_t __attribute__((ext_vector_type(2)));   // cvt_pkrtz result type
typedef float    f32x4 __attribute__((ext_vector_type(4)));
typedef unsigned int u32;

// ws layout (bytes):
//  Qh: [B][N][64]  f16 at 0         (2 MB)   Q pre-scaled by log2(e)
//  Kh: [B][N][64]  f16 at 2 MB      (2 MB)
//  Vg: [B][64 jt][128 c][64 pos] f16 at 4 MB (4 MB)  -- fragment-major V
//  pPart: [B][32 it][S][128 c][128 q] f16 at 8 MB  (S x 4 MB)  NORMALIZED o/l
//  pMl:   [B][32 it][S][128 q][2]   f32 after      (S x 128 KB)

#define QKV_BYTES   8388608ull
#define PART_PER_S  4194304ull
#define ML_PER_S    131072ull
#define LOG2E       1.44269504f

// ---------------------------------------------------------------------------
// Kernel 1: QKV projection via MFMA -- R20 VERBATIM (proven).
// ---------------------------------------------------------------------------
__global__ __launch_bounds__(256) void qkv_proj(
    const float* __restrict__ x,
    const float* __restrict__ Wq, const float* __restrict__ bq,
    const float* __restrict__ Wk, const float* __restrict__ bk,
    const float* __restrict__ Wv, const float* __restrict__ bv,
    _Float16* __restrict__ Qh, _Float16* __restrict__ Kh, _Float16* __restrict__ Vg)
{
    __shared__ _Float16 XsT[64][136];

    const int nt   = blockIdx.x;
    const int ot   = blockIdx.y;
    const int b    = blockIdx.z;
    const int tid  = threadIdx.x;
    const int w    = tid >> 6;
    const int lane = tid & 63;
    const int g    = lane >> 4;
    const int ln   = lane & 15;
    const int nbase = nt * 64;

    const float* xb = x + (size_t)b * Cn * Nn + nbase;
    #pragma unroll
    for (int u = 0; u < 8; ++u) {
        int f  = tid + u * 256;
        int c  = f >> 4;
        int n4 = (f & 15) * 4;
        float4 v = *(const float4*)&xb[(size_t)c * Nn + n4];
        XsT[n4 + 0][c] = (_Float16)v.x;
        XsT[n4 + 1][c] = (_Float16)v.y;
        XsT[n4 + 2][c] = (_Float16)v.z;
        XsT[n4 + 3][c] = (_Float16)v.w;
    }
    __syncthreads();

    const float* Wsrc; const float* bsrc;
    if      (ot == 0) { Wsrc = Wq;            bsrc = bq;      }
    else if (ot == 1) { Wsrc = Wk;            bsrc = bk;      }
    else if (ot == 2) { Wsrc = Wv;            bsrc = bv;      }
    else              { Wsrc = Wv + 64 * Cn;  bsrc = bv + 64; }

    union H8 { h8_t h; _Float16 e[8]; };

    const int os = w;
    f32x4 acc[4];
    #pragma unroll
    for (int ns = 0; ns < 4; ++ns) acc[ns] = (f32x4){0.f, 0.f, 0.f, 0.f};

    #pragma unroll
    for (int kc = 0; kc < 4; ++kc) {
        const float* wp = Wsrc + (size_t)(os * 16 + ln) * Cn + kc * 32 + 8 * g;
        float4 wa = *(const float4*)wp;
        float4 wb = *(const float4*)(wp + 4);
        H8 t;
        t.e[0] = (_Float16)wa.x; t.e[1] = (_Float16)wa.y;
        t.e[2] = (_Float16)wa.z; t.e[3] = (_Float16)wa.w;
        t.e[4] = (_Float16)wb.x; t.e[5] = (_Float16)wb.y;
        t.e[6] = (_Float16)wb.z; t.e[7] = (_Float16)wb.w;
        const h8_t wf = t.h;
        #pragma unroll
        for (int ns = 0; ns < 4; ++ns) {
            const h8_t xv = *(const h8_t*)&XsT[ns * 16 + ln][kc * 32 + 8 * g];
            acc[ns] = __builtin_amdgcn_mfma_f32_16x16x32_f16(wf, xv, acc[ns], 0, 0, 0);
        }
    }

    if (ot <= 1) {
        union H4 { _Float16 e[4]; short4 s; };
        _Float16* dst = (ot == 0 ? Qh : Kh) + ((size_t)b * Nn + nbase) * CQn;
        const float sc = (ot == 0) ? LOG2E : 1.f;
        float4 bb = *(const float4*)&bsrc[os * 16 + 4 * g];
        #pragma unroll
        for (int ns = 0; ns < 4; ++ns) {
            H4 h;
            h.e[0] = (_Float16)((acc[ns][0] + bb.x) * sc);
            h.e[1] = (_Float16)((acc[ns][1] + bb.y) * sc);
            h.e[2] = (_Float16)((acc[ns][2] + bb.z) * sc);
            h.e[3] = (_Float16)((acc[ns][3] + bb.w) * sc);
            *(short4*)&dst[(size_t)(ns * 16 + ln) * CQn + os * 16 + 4 * g] = h.s;
        }
    } else {
        _Float16* dst = Vg + (size_t)(b * 64 + nt) * 8192;
        const int cbase = (ot - 2) * 64 + os * 16 + 4 * g;
        #pragma unroll
        for (int ns = 0; ns < 4; ++ns) {
            const int pos = 32 * (ns >> 1) + 8 * ((4 * ns + (ln >> 2)) & 3)
                          + 4 * (ns & 1) + (ln & 3);
            #pragma unroll
            for (int r = 0; r < 4; ++r) {
                dst[(size_t)(cbase + r) * 64 + pos] =
                    (_Float16)(acc[ns][r] + bsrc[os * 16 + 4 * g + r]);
            }
        }
    }
}

// ---------------------------------------------------------------------------
// Kernel 2: MFMA flash attention, 32 QUERIES PER WAVE (2 x 16-query groups
// A/B sharing every K/V fragment read -> LDS read volume HALVED: R22+R23
// showed the 4-wave shared-operand redundancy (~1.57 GB LDS reads) is the
// binding pipe, and moving it to L2 (R23) is no better). Block = 128
// queries; grid (32, B, S) = 512 blocks (2/CU). LDS padded to 40 KB ->
// allocator caps occupancy at 3 blocks/CU -> 170-VGPR budget (model
// validated R13/R22/R23); demand ~135. Schedule = R22's proven 2-barrier:
// scores -> bar#1 -> stageK(t+1) -> softmax A,B -> PV -> bar#2 -> stageV(t+1).
// ---------------------------------------------------------------------------
__device__ __forceinline__ void gload16(const void* g, void* l) {
    __builtin_amdgcn_global_load_lds(
        (const __attribute__((address_space(1))) u32*)g,
        (__attribute__((address_space(3))) u32*)l, 16, 0, 0);
}

#define KOFF 0           // K buffer: 2 x 8 KB (double)
#define VOFF 16384       // V buffer: 16 KB (single)
// bytes 32768..40959: dead pad -> 3 blocks/CU cap -> 170-VGPR budget

__global__ __launch_bounds__(256) void attn_split(
    const _Float16* __restrict__ Qh, const _Float16* __restrict__ Kh,
    const _Float16* __restrict__ Vg, float* __restrict__ out,
    _Float16* __restrict__ pPart, float* __restrict__ pMl, int S)
{
    __shared__ __align__(16) char smem[40960];

    const int tid  = threadIdx.x;
    const int w    = tid >> 6;
    const int lane = tid & 63;
    const int g    = lane >> 4;
    const int ln   = lane & 15;
    const int it   = blockIdx.x;
    const int b    = blockIdx.y;
    const int s    = blockIdx.z;
    const int wib  = it * 128 + w * 32;   // wave's 32-query base
    const int njt  = 64 / S;

    // Q fragments for both groups (queries wib+ln and wib+16+ln)
    const _Float16* qra = Qh + ((size_t)(b * Nn + wib + ln)) * CQn + 8 * g;
    const _Float16* qrb = qra + 16 * CQn;
    const h8_t qA0 = *(const h8_t*)(qra);
    const h8_t qA1 = *(const h8_t*)(qra + 32);
    const h8_t qB0 = *(const h8_t*)(qrb);
    const h8_t qB1 = *(const h8_t*)(qrb + 32);

    const _Float16* Kb  = Kh + (size_t)b * Nn * CQn;
    const _Float16* Vgb = Vg + (size_t)b * 64 * 8192;

    int ks[2];
    #pragma unroll
    for (int u = 0; u < 2; ++u) {
        int G   = u * 256 + tid;
        int row = G >> 3;
        ks[u] = row * CQn + (((G & 7) ^ (row & 7)) * 8);
    }
    int vs[4];
    #pragma unroll
    for (int u = 0; u < 4; ++u) {
        int G   = u * 256 + tid;
        int row = G >> 3;
        vs[u] = row * 64 + (((G & 7) ^ (row & 7)) * 8);
    }

    const int r7  = ln & 7;
    const int kb0 = ln * 128 + (((    g) ^ r7) << 4);
    const int kb1 = ln * 128 + (((4 + g) ^ r7) << 4);

    auto stageK = [&](int koff, int jt) {
        const _Float16* src = Kb + (size_t)jt * 64 * CQn;
        #pragma unroll
        for (int u = 0; u < 2; ++u)
            gload16(src + ks[u], smem + koff + u * 4096 + w * 1024);
    };
    auto stageV = [&](int jt) {
        const _Float16* src = Vgb + (size_t)jt * 8192;
        #pragma unroll
        for (int u = 0; u < 4; ++u)
            gload16(src + vs[u], smem + VOFF + u * 4096 + w * 1024);
    };

    f32x4 oaccA[8], oaccB[8];
    #pragma unroll
    for (int i = 0; i < 8; ++i) {
        oaccA[i] = (f32x4){0.f, 0.f, 0.f, 0.f};
        oaccB[i] = (f32x4){0.f, 0.f, 0.f, 0.f};
    }
    float mA = -3.0e38f, lA = 0.f;
    float mB = -3.0e38f, lB = 0.f;

    // per-group softmax + P-pack (exp2 domain, defer-max THR = 11.54)
    auto softmax_pack = [&](f32x4 (&st)[4], float& m_run, float& l_run,
                            f32x4 (&oacc)[8], h8_t& pa0, h8_t& pa1) {
        float tmax = st[0][0];
        #pragma unroll
        for (int js = 0; js < 4; ++js)
            #pragma unroll
            for (int r = 0; r < 4; ++r) tmax = fmaxf(tmax, st[js][r]);
        tmax = fmaxf(tmax, __shfl_xor(tmax, 16));
        tmax = fmaxf(tmax, __shfl_xor(tmax, 32));
        if (__any(tmax > m_run + 11.54f)) {
            const float mnew  = fmaxf(m_run, tmax);
            const float alpha = __builtin_amdgcn_exp2f(m_run - mnew);
            const float a0 = __shfl(alpha, 4 * g + 0);
            const float a1 = __shfl(alpha, 4 * g + 1);
            const float a2 = __shfl(alpha, 4 * g + 2);
            const float a3 = __shfl(alpha, 4 * g + 3);
            #pragma unroll
            for (int cs = 0; cs < 8; ++cs) {
                oacc[cs][0] *= a0; oacc[cs][1] *= a1;
                oacc[cs][2] *= a2; oacc[cs][3] *= a3;
            }
            l_run *= alpha;
            m_run = mnew;
        }
        float ts = 0.f;
        #pragma unroll
        for (int js = 0; js < 4; ++js)
            #pragma unroll
            for (int r = 0; r < 4; ++r) {
                float p = __builtin_amdgcn_exp2f(st[js][r] - m_run);
                st[js][r] = p;
                ts += p;
            }
        ts += __shfl_xor(ts, 16);
        ts += __shfl_xor(ts, 32);
        l_run += ts;

        union H8P { h8_t h; p2_t p2[4]; };
        H8P p0u, p1u;
        p0u.p2[0] = __builtin_amdgcn_cvt_pkrtz(st[0][0], st[0][1]);
        p0u.p2[1] = __builtin_amdgcn_cvt_pkrtz(st[0][2], st[0][3]);
        p0u.p2[2] = __builtin_amdgcn_cvt_pkrtz(st[1][0], st[1][1]);
        p0u.p2[3] = __builtin_amdgcn_cvt_pkrtz(st[1][2], st[1][3]);
        p1u.p2[0] = __builtin_amdgcn_cvt_pkrtz(st[2][0], st[2][1]);
        p1u.p2[1] = __builtin_amdgcn_cvt_pkrtz(st[2][2], st[2][3]);
        p1u.p2[2] = __builtin_amdgcn_cvt_pkrtz(st[3][0], st[3][1]);
        p1u.p2[3] = __builtin_amdgcn_cvt_pkrtz(st[3][2], st[3][3]);
        pa0 = p0u.h;
        pa1 = p1u.h;
    };

    const int jt0 = s * njt;
    stageK(KOFF, jt0);
    stageV(jt0);
    __syncthreads();

    for (int t = 0; t < njt; ++t) {
        // 1) scores for BOTH groups from one K read
        const char* KU = smem + KOFF + ((t & 1) ? 8192 : 0);
        f32x4 stA[4], stB[4];
        __builtin_amdgcn_s_setprio(1);
        #pragma unroll
        for (int js = 0; js < 4; ++js) {
            h8_t k0 = *(const h8_t*)(KU + kb0 + js * 2048);
            h8_t k1 = *(const h8_t*)(KU + kb1 + js * 2048);
            stA[js] = (f32x4){0.f, 0.f, 0.f, 0.f};
            stA[js] = __builtin_amdgcn_mfma_f32_16x16x32_f16(k0, qA0, stA[js], 0, 0, 0);
            stA[js] = __builtin_amdgcn_mfma_f32_16x16x32_f16(k1, qA1, stA[js], 0, 0, 0);
            stB[js] = (f32x4){0.f, 0.f, 0.f, 0.f};
            stB[js] = __builtin_amdgcn_mfma_f32_16x16x32_f16(k0, qB0, stB[js], 0, 0, 0);
            stB[js] = __builtin_amdgcn_mfma_f32_16x16x32_f16(k1, qB1, stB[js], 0, 0, 0);
        }
        __builtin_amdgcn_s_setprio(0);

        __syncthreads();   // bar#1: drains V(t) stage; all K reads retired

        // 2) stage next K (drains at bar#2 under softmax+PV cover)
        if (t + 1 < njt) stageK(KOFF + ((t & 1) ? 0 : 8192), jt0 + t + 1);

        // 3) softmax + P-pack per group
        h8_t paA0, paA1, paB0, paB1;
        softmax_pack(stA, mA, lA, oaccA, paA0, paA1);
        softmax_pack(stB, mB, lB, oaccB, paB0, paB1);

        // 4) PV for BOTH groups from one V read
        __builtin_amdgcn_s_setprio(1);
        #pragma unroll
        for (int cs = 0; cs < 8; ++cs) {
            h8_t v01 = *(const h8_t*)(smem + VOFF + kb0 + cs * 2048);
            h8_t v23 = *(const h8_t*)(smem + VOFF + kb1 + cs * 2048);
            oaccA[cs] = __builtin_amdgcn_mfma_f32_16x16x32_f16(paA0, v01, oaccA[cs], 0, 0, 0);
            oaccA[cs] = __builtin_amdgcn_mfma_f32_16x16x32_f16(paA1, v23, oaccA[cs], 0, 0, 0);
            oaccB[cs] = __builtin_amdgcn_mfma_f32_16x16x32_f16(paB0, v01, oaccB[cs], 0, 0, 0);
            oaccB[cs] = __builtin_amdgcn_mfma_f32_16x16x32_f16(paB1, v23, oaccB[cs], 0, 0, 0);
        }
        __builtin_amdgcn_s_setprio(0);

        __syncthreads();   // bar#2: drains K(t+1); all V reads retired

        // 5) stage next V (drains at next bar#1 under scores cover)
        if (t + 1 < njt) stageV(jt0 + t + 1);
    }

    // epilogue per group
    auto epilogue = [&](f32x4 (&oacc)[8], float m_run, float l_run, int h) {
        const float lr = 1.f / l_run;
        const float l0 = __shfl(lr, 4 * g + 0);
        const float l1 = __shfl(lr, 4 * g + 1);
        const float l2 = __shfl(lr, 4 * g + 2);
        const float l3 = __shfl(lr, 4 * g + 3);
        if (S == 1) {
            float* ob = out + (size_t)b * Cn * Nn;
            #pragma unroll
            for (int cs = 0; cs < 8; ++cs) {
                float4 o;
                o.x = oacc[cs][0] * l0;
                o.y = oacc[cs][1] * l1;
                o.z = oacc[cs][2] * l2;
                o.w = oacc[cs][3] * l3;
                *(float4*)&ob[(size_t)(cs * 16 + ln) * Nn + wib + 16 * h + 4 * g] = o;
            }
        } else {
            union H4 { _Float16 e[4]; short4 sv; };
            _Float16* pp = pPart + (((size_t)b * 32 + it) * S + s) * 16384;
            const int qloc = w * 32 + 16 * h + 4 * g;
            #pragma unroll
            for (int cs = 0; cs < 8; ++cs) {
                H4 hh;
                hh.e[0] = (_Float16)(oacc[cs][0] * l0);
                hh.e[1] = (_Float16)(oacc[cs][1] * l1);
                hh.e[2] = (_Float16)(oacc[cs][2] * l2);
                hh.e[3] = (_Float16)(oacc[cs][3] * l3);
                *(short4*)&pp[(size_t)(cs * 16 + ln) * 128 + qloc] = hh.sv;
            }
            if (g == 0) {
                float* ml = pMl + ((((size_t)b * 32 + it) * S + s) * 128
                                   + w * 32 + 16 * h + ln) * 2;
                ml[0] = m_run;
                ml[1] = l_run;
            }
        }
    };
    epilogue(oaccA, mA, lA, 0);
    epilogue(oaccB, mB, lB, 1);
}

// ---------------------------------------------------------------------------
// Kernel 3: flash-combine across S splits (128 q x 128 c per it-tile).
// grid (32 it, B, 4 c-quarters) = 512 blocks, 256 threads.
// Thread: c = ch*32 + (tid>>3), 16 queries at q0 = (tid&7)*16.
// ---------------------------------------------------------------------------
__global__ __launch_bounds__(256) void attn_combine(
    const _Float16* __restrict__ pPart, const float* __restrict__ pMl,
    float* __restrict__ out, int S)
{
    const int it  = blockIdx.x;
    const int b   = blockIdx.y;
    const int ch  = blockIdx.z;
    const int tid = threadIdx.x;

    __shared__ float wgt[4][128];
    __shared__ float linv[128];

    if (tid < 128) {
        const float* mlb = pMl + (((size_t)b * 32 + it) * S * 128 + tid) * 2;
        float ms[4], ls[4], m = -3.0e38f;
        for (int s = 0; s < S; ++s) {
            ms[s] = mlb[s * 256 + 0];
            ls[s] = mlb[s * 256 + 1];
            m = fmaxf(m, ms[s]);
        }
        float l = 0.f;
        for (int s = 0; s < S; ++s) {
            float wv = ls[s] * __builtin_amdgcn_exp2f(ms[s] - m);
            wgt[s][tid] = wv;
            l += wv;
        }
        linv[tid] = 1.f / l;
    }
    __syncthreads();

    const int c  = ch * 32 + (tid >> 3);
    const int q0 = (tid & 7) * 16;
    const _Float16* base = pPart + ((size_t)b * 32 + it) * S * 16384 + (size_t)c * 128 + q0;

    float acc[16];
    #pragma unroll
    for (int k = 0; k < 16; ++k) acc[k] = 0.f;
    for (int s = 0; s < S; ++s) {
        const _Float16* ps = base + (size_t)s * 16384;
        #pragma unroll
        for (int k = 0; k < 16; k += 8) {
            h8_t v = *(const h8_t*)(ps + k);
            #pragma unroll
            for (int j = 0; j < 8; ++j)
                acc[k + j] += wgt[s][q0 + k + j] * (float)v[j];
        }
    }
    float* ob = out + ((size_t)b * Cn + c) * Nn + it * 128 + q0;
    #pragma unroll
    for (int k = 0; k < 16; k += 4) {
        float4 o;
        o.x = acc[k + 0] * linv[q0 + k + 0];
        o.y = acc[k + 1] * linv[q0 + k + 1];
        o.z = acc[k + 2] * linv[q0 + k + 2];
        o.w = acc[k + 3] * linv[q0 + k + 3];
        *(float4*)&ob[k] = o;
    }
}

extern "C" void kernel_launch(void* const* d_in, const int* in_sizes, int n_in,
                              void* d_out, int out_size, void* d_ws, size_t ws_size,
                              hipStream_t stream) {
    const float* x  = (const float*)d_in[0];
    const float* Wq = (const float*)d_in[1];
    const float* bq = (const float*)d_in[2];
    const float* Wk = (const float*)d_in[3];
    const float* bk = (const float*)d_in[4];
    const float* Wv = (const float*)d_in[5];
    const float* bv = (const float*)d_in[6];
    float* out = (float*)d_out;

    _Float16* ws = (_Float16*)d_ws;
    _Float16* Qh = ws;
    _Float16* Kh = ws + 1048576;
    _Float16* Vg = ws + 2097152;

    int S = 1;
    if (ws_size >= QKV_BYTES + 4 * (PART_PER_S + ML_PER_S)) S = 4;
    else if (ws_size >= QKV_BYTES + 2 * (PART_PER_S + ML_PER_S)) S = 2;

    _Float16* pPart = (_Float16*)((char*)d_ws + QKV_BYTES);
    float*    pMl   = (float*)((char*)d_ws + QKV_BYTES + (size_t)S * PART_PER_S);

    dim3 gproj(Nn / 64, 4, Bn);
    qkv_proj<<<gproj, 256, 0, stream>>>(x, Wq, bq, Wk, bk, Wv, bv, Qh, Kh, Vg);

    dim3 gattn(Nn / 128, Bn, S);
    attn_split<<<gattn, 256, 0, stream>>>(Qh, Kh, Vg, out, pPart, pMl, S);

    if (S > 1) {
        dim3 gcomb(Nn / 128, Bn, 4);
        attn_combine<<<gcomb, 256, 0, stream>>>(pPart, pMl, out, S);
    }
}